// Round 1
// baseline (194.227 us; speedup 1.0000x reference)
//
#include <hip/hip_runtime.h>
#include <math.h>

#define L 64
#define D 512
#define E 8
#define F 256
#define NEG_INF -1e30f

// ---------------- Kernel A: proj[e][d] = sum_o Wk[e][o][d] * q[e][o] ----------------
__global__ void proj_kernel(const float* __restrict__ Wk, const float* __restrict__ q,
                            float* __restrict__ proj) {
    int idx = blockIdx.x * blockDim.x + threadIdx.x;   // 0..E*D-1
    int e = idx >> 9;          // / D
    int d = idx & (D - 1);
    const float* wbase = Wk + (size_t)e * D * D + d;
    const float* qbase = q + e * D;
    float acc = 0.f;
    #pragma unroll 8
    for (int o = 0; o < D; ++o)
        acc += wbase[(size_t)o * D] * qbase[o];
    proj[idx] = acc;
}

// ---------------- Kernel B: per-row MoE pooling ----------------
// grid = N blocks, 512 threads. Dynamic LDS: 64*512 f32 = 128 KiB token embeddings.
__launch_bounds__(512, 1)
__global__ void row_kernel(const int* __restrict__ sample,
                           const float* __restrict__ emb_table,
                           const float* __restrict__ proj,
                           const float* __restrict__ gate_W,
                           const float* __restrict__ gate_b,
                           float* __restrict__ pooled) {
    extern __shared__ float emb[];        // [L][D]
    __shared__ int   idx_s[L];
    __shared__ float msk[L];
    __shared__ float scr[2 * L];          // scores for the 2 selected experts
    __shared__ float att2[2 * L];
    __shared__ float cf[L];
    __shared__ float red[64];             // 8 waves x 8 experts
    __shared__ float gsc[E];
    __shared__ float pr[2 * D];           // selected proj rows
    __shared__ float wsel[2];
    __shared__ int   esel[2];
    __shared__ int   allpad;

    const int n    = blockIdx.x;
    const int tid  = threadIdx.x;
    const int lane = tid & 63;
    const int wv   = tid >> 6;            // 0..7

    if (tid < L) {
        int ix = sample[n * L + tid];
        idx_s[tid] = ix;
        msk[tid] = (ix != 0) ? 1.f : 0.f;  // PAD==0
    }
    __syncthreads();

    // ---- stage token embeddings: wave wv handles rows wv*8 .. wv*8+7 ----
    for (int j = 0; j < 8; ++j) {
        int l = wv * 8 + j;
        const float4* src = (const float4*)(emb_table + (size_t)idx_s[l] * D);
        float4* dst = (float4*)(emb + l * D);
        dst[lane]      = src[lane];
        dst[lane + 64] = src[lane + 64];
    }
    __syncthreads();

    // ---- gate input: mean over tokens (pads contribute exact 0) ----
    float g = 0.f;
    #pragma unroll
    for (int l = 0; l < L; ++l)
        g += msk[l] * emb[l * D + tid];
    const float gi = g * (1.f / 64.f);     // exact /64, matches reference mean

    // ---- gate scores: per-thread partials, wave reduce, cross-wave reduce ----
    float p[E];
    #pragma unroll
    for (int e = 0; e < E; ++e)
        p[e] = gi * gate_W[e * D + tid];
    #pragma unroll
    for (int e = 0; e < E; ++e) {
        float v = p[e];
        #pragma unroll
        for (int off = 32; off; off >>= 1) v += __shfl_xor(v, off, 64);
        if (lane == 0) red[wv * E + e] = v;
    }
    __syncthreads();
    if (tid < E) {
        float s = gate_b[tid];
        #pragma unroll
        for (int w = 0; w < 8; ++w) s += red[w * E + tid];
        gsc[tid] = s;
    }
    __syncthreads();

    // ---- top-2 + softmax over the two (jax tie-break: first index) ----
    if (tid == 0) {
        int b0 = 0; float v0 = gsc[0];
        for (int e = 1; e < E; ++e) if (gsc[e] > v0) { v0 = gsc[e]; b0 = e; }
        int b1 = -1; float v1 = -3.4e38f;
        for (int e = 0; e < E; ++e) if (e != b0 && gsc[e] > v1) { v1 = gsc[e]; b1 = e; }
        float ex  = expf(v1 - v0);         // v0 is the max
        float inv = 1.f / (1.f + ex);
        wsel[0] = inv; wsel[1] = ex * inv;
        esel[0] = b0;  esel[1] = b1;
        float cnt = 0.f;
        for (int l = 0; l < L; ++l) cnt += msk[l];
        allpad = (cnt == 0.f) ? 1 : 0;
    }
    __syncthreads();

    // ---- stage the 2 selected proj rows into LDS ----
    for (int i = tid; i < 2 * D; i += 512) {
        int k = i >> 9;
        int d = i & (D - 1);
        pr[i] = proj[esel[k] * D + d];
    }
    __syncthreads();

    // ---- score dots: wave per token, lanes over D (float4, conflict-free) ----
    {
        const float4* pr4 = (const float4*)pr;
        float4 b00 = pr4[lane],       b01 = pr4[64 + lane];
        float4 b10 = pr4[128 + lane], b11 = pr4[192 + lane];
        for (int j = 0; j < 8; ++j) {
            int l = wv * 8 + j;
            const float4* e4 = (const float4*)(emb + l * D);
            float4 a0 = e4[lane], a1 = e4[64 + lane];
            float s0 = a0.x*b00.x + a0.y*b00.y + a0.z*b00.z + a0.w*b00.w
                     + a1.x*b01.x + a1.y*b01.y + a1.z*b01.z + a1.w*b01.w;
            float s1 = a0.x*b10.x + a0.y*b10.y + a0.z*b10.z + a0.w*b10.w
                     + a1.x*b11.x + a1.y*b11.y + a1.z*b11.z + a1.w*b11.w;
            #pragma unroll
            for (int off = 32; off; off >>= 1) {
                s0 += __shfl_xor(s0, off, 64);
                s1 += __shfl_xor(s1, off, 64);
            }
            if (lane == 0) {
                bool real = (msk[l] != 0.f);
                scr[l]     = real ? s0 : NEG_INF;
                scr[L + l] = real ? s1 : NEG_INF;
            }
        }
    }
    __syncthreads();

    // ---- masked softmax over L for the 2 selected experts ----
    if (tid < 128) {
        int k = wv;                        // 0 or 1
        float s = scr[k * L + lane];
        float m = s;
        #pragma unroll
        for (int off = 32; off; off >>= 1) m = fmaxf(m, __shfl_xor(m, off, 64));
        float pex = expf(s - m);           // masked: exp(-huge) -> 0
        float sum = pex;
        #pragma unroll
        for (int off = 32; off; off >>= 1) sum += __shfl_xor(sum, off, 64);
        att2[k * L + lane] = pex / sum;
    }
    __syncthreads();
    if (tid < L) cf[tid] = wsel[0] * att2[tid] + wsel[1] * att2[L + tid];
    __syncthreads();

    // ---- pooled[d] = sum_l cf[l] * emb[l][d] ----
    float acc = 0.f;
    #pragma unroll
    for (int l = 0; l < L; ++l)
        acc += cf[l] * emb[l * D + tid];
    if (allpad) acc = 0.f;
    pooled[(size_t)n * D + tid] = acc;
}

// ---------------- Kernel C: out = gelu(pooled @ trans_W^T + b), 8 rows/block ----------------
__launch_bounds__(256, 1)
__global__ void out_kernel(const float* __restrict__ pooled,
                           const float* __restrict__ trans_W,
                           const float* __restrict__ trans_b,
                           float* __restrict__ out) {
    __shared__ float pl[8 * D];           // 16 KiB
    const int tid = threadIdx.x;          // = output feature f
    const int n0  = blockIdx.x * 8;
    for (int i = tid; i < 8 * D; i += 256)
        pl[i] = pooled[(size_t)n0 * D + i];
    __syncthreads();

    const float4* w4  = (const float4*)(trans_W + (size_t)tid * D);
    const float4* pl4 = (const float4*)pl;
    float acc[8] = {0.f, 0.f, 0.f, 0.f, 0.f, 0.f, 0.f, 0.f};
    #pragma unroll 4
    for (int d4 = 0; d4 < 128; ++d4) {
        float4 w = w4[d4];
        #pragma unroll
        for (int r = 0; r < 8; ++r) {
            float4 pv = pl4[r * 128 + d4];   // LDS broadcast
            acc[r] += w.x*pv.x + w.y*pv.y + w.z*pv.z + w.w*pv.w;
        }
    }
    float b = trans_b[tid];
    #pragma unroll
    for (int r = 0; r < 8; ++r) {
        float x = acc[r] + b;
        out[(size_t)(n0 + r) * F + tid] = 0.5f * x * (1.f + erff(x * 0.70710678118654752f));
    }
}

extern "C" void kernel_launch(void* const* d_in, const int* in_sizes, int n_in,
                              void* d_out, int out_size, void* d_ws, size_t ws_size,
                              hipStream_t stream) {
    const int*   sample    = (const int*)d_in[0];
    const float* emb_table = (const float*)d_in[1];
    const float* expert_q  = (const float*)d_in[2];
    const float* expert_Wk = (const float*)d_in[3];
    const float* gate_W    = (const float*)d_in[4];
    const float* gate_b    = (const float*)d_in[5];
    const float* trans_W   = (const float*)d_in[6];
    const float* trans_b   = (const float*)d_in[7];
    float* out = (float*)d_out;

    const int N = in_sizes[0] / L;                 // B*T = 2048

    float* proj   = (float*)d_ws;                  // E*D
    float* pooled = proj + E * D;                  // N*D
    (void)ws_size; (void)n_in; (void)out_size;

    // opt in to >64 KiB dynamic LDS (non-stream API; graph-capture safe, idempotent)
    (void)hipFuncSetAttribute(reinterpret_cast<const void*>(row_kernel),
                              hipFuncAttributeMaxDynamicSharedMemorySize,
                              L * D * (int)sizeof(float));

    proj_kernel<<<(E * D) / 256, 256, 0, stream>>>(expert_Wk, expert_q, proj);
    row_kernel<<<N, 512, L * D * sizeof(float), stream>>>(sample, emb_table, proj,
                                                          gate_W, gate_b, pooled);
    out_kernel<<<N / 8, 256, 0, stream>>>(pooled, trans_W, trans_b, out);
}

// Round 2
// 112.943 us; speedup vs baseline: 1.7197x; 1.7197x over previous
//
#include <hip/hip_runtime.h>
#include <math.h>

#define L 64
#define D 512
#define E 8
#define F 256
#define NEG_INF -1e30f

// ---------- proj stage A: partial over o-chunks (grid: E*8 blocks, 512 thr) ----------
__global__ void projA_kernel(const float* __restrict__ Wk, const float* __restrict__ q,
                             float* __restrict__ part) {
    const int e = blockIdx.x >> 3, oc = blockIdx.x & 7;
    const int d = threadIdx.x;
    const float* wb = Wk + ((size_t)e * D + oc * 64) * D + d;
    const float* qb = q + e * D + oc * 64;
    float acc = 0.f;
    #pragma unroll 8
    for (int o = 0; o < 64; ++o) acc += wb[(size_t)o * D] * qb[o];
    part[(size_t)blockIdx.x * D + d] = acc;
}

// ---------- proj stage B: combine 8 partials ----------
__global__ void projB_kernel(const float* __restrict__ part, float* __restrict__ proj) {
    const int i = blockIdx.x * blockDim.x + threadIdx.x;   // 0..E*D-1
    const int e = i >> 9, d = i & (D - 1);
    float s = 0.f;
    #pragma unroll
    for (int oc = 0; oc < 8; ++oc) s += part[(size_t)(e * 8 + oc) * D + d];
    proj[i] = s;
}

// ---------- transpose trans_W -> wT[d][f] (grid: D blocks, F threads) ----------
__global__ void transp_kernel(const float* __restrict__ W, float* __restrict__ wT) {
    const int d = blockIdx.x, f = threadIdx.x;
    wT[(size_t)d * F + f] = W[(size_t)f * D + d];
}

// ---------- Kernel B: per-row MoE pooling, embeddings in REGISTERS ----------
// 512 threads = 8 waves; wave wv owns tokens wv*8..wv*8+7; lane holds 8 floats
// per token (float4 at [lane] and [lane+64] of the 128-float4 row).
__launch_bounds__(512, 4)   // 4 waves/SIMD -> 2 blocks/CU, caps VGPR at 128
__global__ void row_kernel(const int* __restrict__ sample,
                           const float* __restrict__ emb_table,
                           const float* __restrict__ proj,
                           const float* __restrict__ gate_W,
                           const float* __restrict__ gate_b,
                           float* __restrict__ pooled) {
    __shared__ float red[8][D];     // 16 KiB cross-wave reduce buffer
    __shared__ int   idx_s[L];
    __shared__ float msk[L];
    __shared__ float scr[2][L];
    __shared__ float att2[2][L];
    __shared__ float cf[L];
    __shared__ float gred[64];      // 8 waves x 8 experts
    __shared__ float gsc[E];
    __shared__ float wsel[2];
    __shared__ int   esel[2];
    __shared__ int   allpad;

    const int n    = blockIdx.x;
    const int tid  = threadIdx.x;
    const int lane = tid & 63;
    const int wv   = tid >> 6;

    if (tid < L) {
        int ix = sample[n * L + tid];
        idx_s[tid] = ix;
        msk[tid] = (ix != 0) ? 1.f : 0.f;   // PAD==0
    }
    __syncthreads();

    // ---- gather token embeddings into registers ----
    float4 a0[8], a1[8];
    #pragma unroll
    for (int j = 0; j < 8; ++j) {
        const float4* src = (const float4*)(emb_table + (size_t)idx_s[wv * 8 + j] * D);
        a0[j] = src[lane];
        a1[j] = src[lane + 64];
    }

    // ---- gate mean: in-wave partial over 8 tokens, cross-wave via LDS ----
    {
        float4 s0 = {0.f, 0.f, 0.f, 0.f}, s1 = {0.f, 0.f, 0.f, 0.f};
        #pragma unroll
        for (int j = 0; j < 8; ++j) {
            float m = msk[wv * 8 + j];
            s0.x += m * a0[j].x; s0.y += m * a0[j].y; s0.z += m * a0[j].z; s0.w += m * a0[j].w;
            s1.x += m * a1[j].x; s1.y += m * a1[j].y; s1.z += m * a1[j].z; s1.w += m * a1[j].w;
        }
        ((float4*)red[wv])[lane]      = s0;
        ((float4*)red[wv])[lane + 64] = s1;
    }
    __syncthreads();

    float g = 0.f;
    #pragma unroll
    for (int w = 0; w < 8; ++w) g += red[w][tid];
    const float gi = g * (1.f / 64.f);      // exact /64, matches reference mean

    // ---- gate scores ----
    {
        float p[E];
        #pragma unroll
        for (int e = 0; e < E; ++e) p[e] = gi * gate_W[e * D + tid];
        #pragma unroll
        for (int e = 0; e < E; ++e) {
            float v = p[e];
            #pragma unroll
            for (int off = 32; off; off >>= 1) v += __shfl_xor(v, off, 64);
            if (lane == 0) gred[wv * E + e] = v;
        }
    }
    __syncthreads();
    if (tid < E) {
        float s = gate_b[tid];
        #pragma unroll
        for (int w = 0; w < 8; ++w) s += gred[w * E + tid];
        gsc[tid] = s;
    }
    __syncthreads();

    // ---- top-2 + softmax over the two (first-index tie-break like lax.top_k) ----
    if (tid == 0) {
        int b0 = 0; float v0 = gsc[0];
        for (int e = 1; e < E; ++e) if (gsc[e] > v0) { v0 = gsc[e]; b0 = e; }
        int b1 = -1; float v1 = -3.4e38f;
        for (int e = 0; e < E; ++e) if (e != b0 && gsc[e] > v1) { v1 = gsc[e]; b1 = e; }
        float ex  = expf(v1 - v0);
        float inv = 1.f / (1.f + ex);
        wsel[0] = inv; wsel[1] = ex * inv;
        esel[0] = b0;  esel[1] = b1;
        float cnt = 0.f;
        for (int l = 0; l < L; ++l) cnt += msk[l];
        allpad = (cnt == 0.f) ? 1 : 0;
    }
    __syncthreads();

    // ---- score dots for the 2 selected experts (proj rows read direct, L2-hot) ----
    {
        const float4* pe0 = (const float4*)(proj + esel[0] * D);
        const float4* pe1 = (const float4*)(proj + esel[1] * D);
        float4 b00 = pe0[lane], b01 = pe0[lane + 64];
        float4 b10 = pe1[lane], b11 = pe1[lane + 64];
        #pragma unroll
        for (int j = 0; j < 8; ++j) {
            float s0 = a0[j].x*b00.x + a0[j].y*b00.y + a0[j].z*b00.z + a0[j].w*b00.w
                     + a1[j].x*b01.x + a1[j].y*b01.y + a1[j].z*b01.z + a1[j].w*b01.w;
            float s1 = a0[j].x*b10.x + a0[j].y*b10.y + a0[j].z*b10.z + a0[j].w*b10.w
                     + a1[j].x*b11.x + a1[j].y*b11.y + a1[j].z*b11.z + a1[j].w*b11.w;
            #pragma unroll
            for (int off = 32; off; off >>= 1) {
                s0 += __shfl_xor(s0, off, 64);
                s1 += __shfl_xor(s1, off, 64);
            }
            if (lane == 0) {
                int l = wv * 8 + j;
                bool real = (msk[l] != 0.f);
                scr[0][l] = real ? s0 : NEG_INF;
                scr[1][l] = real ? s1 : NEG_INF;
            }
        }
    }
    __syncthreads();

    // ---- masked softmax over L for both selected experts ----
    if (tid < 128) {
        int k = wv;                          // 0 or 1
        float s = scr[k][lane];
        float m = s;
        #pragma unroll
        for (int off = 32; off; off >>= 1) m = fmaxf(m, __shfl_xor(m, off, 64));
        float pex = expf(s - m);
        float sum = pex;
        #pragma unroll
        for (int off = 32; off; off >>= 1) sum += __shfl_xor(sum, off, 64);
        att2[k][lane] = pex / sum;
    }
    __syncthreads();
    if (tid < L) cf[tid] = wsel[0] * att2[0][tid] + wsel[1] * att2[1][tid];
    __syncthreads();

    // ---- pooled: in-wave partial over 8 tokens, cross-wave via LDS ----
    {
        float4 s0 = {0.f, 0.f, 0.f, 0.f}, s1 = {0.f, 0.f, 0.f, 0.f};
        #pragma unroll
        for (int j = 0; j < 8; ++j) {
            float c = cf[wv * 8 + j];
            s0.x += c * a0[j].x; s0.y += c * a0[j].y; s0.z += c * a0[j].z; s0.w += c * a0[j].w;
            s1.x += c * a1[j].x; s1.y += c * a1[j].y; s1.z += c * a1[j].z; s1.w += c * a1[j].w;
        }
        ((float4*)red[wv])[lane]      = s0;
        ((float4*)red[wv])[lane + 64] = s1;
    }
    __syncthreads();

    float acc = 0.f;
    #pragma unroll
    for (int w = 0; w < 8; ++w) acc += red[w][tid];
    if (allpad) acc = 0.f;
    pooled[(size_t)n * D + tid] = acc;
}

// ---------- Kernel C: out = gelu(pooled @ wT + b); wave handles 2 rows ----------
__launch_bounds__(256, 4)
__global__ void out_kernel(const float* __restrict__ pooled,
                           const float* __restrict__ wT,     // [D][F]
                           const float* __restrict__ trans_b,
                           float* __restrict__ out) {
    __shared__ float pl[8 * D];             // 16 KiB
    const int tid  = threadIdx.x;
    const int lane = tid & 63;
    const int w    = tid >> 6;              // wave -> rows 2w, 2w+1
    const int n0   = blockIdx.x * 8;

    {
        const float4* src = (const float4*)(pooled + (size_t)n0 * D);
        float4* dst = (float4*)pl;
        #pragma unroll
        for (int i = 0; i < 4; ++i) dst[tid + 256 * i] = src[tid + 256 * i];
    }
    __syncthreads();

    const float* pl0 = pl + (2 * w) * D;
    const float* pl1 = pl0 + D;
    const float4* wT4 = (const float4*)wT;  // [D][F/4]
    float4 acc0 = {0.f,0.f,0.f,0.f}, acc1 = {0.f,0.f,0.f,0.f};
    #pragma unroll 4
    for (int d = 0; d < D; ++d) {
        float4 wt = wT4[d * 64 + lane];     // coalesced 16B/lane
        float p0 = pl0[d], p1 = pl1[d];     // LDS broadcast
        acc0.x += p0*wt.x; acc0.y += p0*wt.y; acc0.z += p0*wt.z; acc0.w += p0*wt.w;
        acc1.x += p1*wt.x; acc1.y += p1*wt.y; acc1.z += p1*wt.z; acc1.w += p1*wt.w;
    }

    float4 b4 = ((const float4*)trans_b)[lane];
    float4 o0, o1;
    #define GELU(v) (0.5f * (v) * (1.f + erff((v) * 0.70710678118654752f)))
    o0.x = GELU(acc0.x + b4.x); o0.y = GELU(acc0.y + b4.y);
    o0.z = GELU(acc0.z + b4.z); o0.w = GELU(acc0.w + b4.w);
    o1.x = GELU(acc1.x + b4.x); o1.y = GELU(acc1.y + b4.y);
    o1.z = GELU(acc1.z + b4.z); o1.w = GELU(acc1.w + b4.w);
    #undef GELU
    ((float4*)(out + (size_t)(n0 + 2 * w) * F))[lane]     = o0;
    ((float4*)(out + (size_t)(n0 + 2 * w + 1) * F))[lane] = o1;
}

extern "C" void kernel_launch(void* const* d_in, const int* in_sizes, int n_in,
                              void* d_out, int out_size, void* d_ws, size_t ws_size,
                              hipStream_t stream) {
    const int*   sample    = (const int*)d_in[0];
    const float* emb_table = (const float*)d_in[1];
    const float* expert_q  = (const float*)d_in[2];
    const float* expert_Wk = (const float*)d_in[3];
    const float* gate_W    = (const float*)d_in[4];
    const float* gate_b    = (const float*)d_in[5];
    const float* trans_W   = (const float*)d_in[6];
    const float* trans_b   = (const float*)d_in[7];
    float* out = (float*)d_out;

    const int N = in_sizes[0] / L;                 // B*T = 2048

    float* proj   = (float*)d_ws;                  // E*D
    float* pooled = proj + E * D;                  // N*D
    float* part   = pooled + (size_t)N * D;        // E*8*D
    float* wT     = part + E * 8 * D;              // D*F
    (void)ws_size; (void)n_in; (void)out_size;

    projA_kernel<<<E * 8, D, 0, stream>>>(expert_Wk, expert_q, part);
    projB_kernel<<<(E * D) / 256, 256, 0, stream>>>(part, proj);
    transp_kernel<<<D, F, 0, stream>>>(trans_W, wT);
    row_kernel<<<N, 512, 0, stream>>>(sample, emb_table, proj, gate_W, gate_b, pooled);
    out_kernel<<<N / 8, 256, 0, stream>>>(pooled, wT, trans_b, out);
}

// Round 3
// 112.910 us; speedup vs baseline: 1.7202x; 1.0003x over previous
//
#include <hip/hip_runtime.h>
#include <math.h>

#define L 64
#define D 512
#define E 8
#define F 256
#define NEG_INF -1e30f

// Opaque register pin: prevents the compiler from rematerializing the value
// from its defining load (which would re-issue the 256MB gather per use phase).
#define PIN4(v) asm volatile("" : "+v"((v).x), "+v"((v).y), "+v"((v).z), "+v"((v).w))

// ---------- proj stage A: partial over o-chunks (grid: E*8 blocks, 512 thr) ----------
__global__ void projA_kernel(const float* __restrict__ Wk, const float* __restrict__ q,
                             float* __restrict__ part) {
    const int e = blockIdx.x >> 3, oc = blockIdx.x & 7;
    const int d = threadIdx.x;
    const float* wb = Wk + ((size_t)e * D + oc * 64) * D + d;
    const float* qb = q + e * D + oc * 64;
    float acc = 0.f;
    #pragma unroll 8
    for (int o = 0; o < 64; ++o) acc += wb[(size_t)o * D] * qb[o];
    part[(size_t)blockIdx.x * D + d] = acc;
}

// ---------- proj stage B: combine 8 partials ----------
__global__ void projB_kernel(const float* __restrict__ part, float* __restrict__ proj) {
    const int i = blockIdx.x * blockDim.x + threadIdx.x;   // 0..E*D-1
    const int e = i >> 9, d = i & (D - 1);
    float s = 0.f;
    #pragma unroll
    for (int oc = 0; oc < 8; ++oc) s += part[(size_t)(e * 8 + oc) * D + d];
    proj[i] = s;
}

// ---------- transpose trans_W -> wT[d][f] (grid: D blocks, F threads) ----------
__global__ void transp_kernel(const float* __restrict__ W, float* __restrict__ wT) {
    const int d = blockIdx.x, f = threadIdx.x;
    wT[(size_t)d * F + f] = W[(size_t)f * D + d];
}

// ---------- Kernel B: per-row MoE pooling, embeddings PINNED in registers ----------
// 512 threads = 8 waves; wave wv owns tokens wv*8..wv*8+7; lane holds 8 floats
// per token (float4 at [lane] and [lane+64] of the 128-float4 row).
__launch_bounds__(512, 4)   // caps VGPR at 128; emb regs (64) + working set fits
__global__ void row_kernel(const int* __restrict__ sample,
                           const float* __restrict__ emb_table,
                           const float* __restrict__ proj,
                           const float* __restrict__ gate_W,
                           const float* __restrict__ gate_b,
                           float* __restrict__ pooled) {
    __shared__ float red[8][D];     // 16 KiB cross-wave reduce buffer
    __shared__ int   idx_s[L];
    __shared__ float msk[L];
    __shared__ float scr[2][L];
    __shared__ float att2[2][L];
    __shared__ float cf[L];
    __shared__ float gred[64];      // 8 waves x 8 experts
    __shared__ float gsc[E];
    __shared__ float wsel[2];
    __shared__ int   esel[2];
    __shared__ int   allpad;

    const int n    = blockIdx.x;
    const int tid  = threadIdx.x;
    const int lane = tid & 63;
    const int wv   = tid >> 6;

    if (tid < L) {
        int ix = sample[n * L + tid];
        idx_s[tid] = ix;
        msk[tid] = (ix != 0) ? 1.f : 0.f;   // PAD==0
    }
    __syncthreads();

    // ---- gather token embeddings into registers (ONCE) ----
    float4 a0[8], a1[8];
    #pragma unroll
    for (int j = 0; j < 8; ++j) {
        const float4* src = (const float4*)(emb_table + (size_t)idx_s[wv * 8 + j] * D);
        a0[j] = src[lane];
        a1[j] = src[lane + 64];
    }
    #pragma unroll
    for (int j = 0; j < 8; ++j) { PIN4(a0[j]); PIN4(a1[j]); }

    // ---- gate mean: in-wave partial over 8 tokens, cross-wave via LDS ----
    {
        float4 s0 = {0.f, 0.f, 0.f, 0.f}, s1 = {0.f, 0.f, 0.f, 0.f};
        #pragma unroll
        for (int j = 0; j < 8; ++j) {
            float m = msk[wv * 8 + j];
            s0.x += m * a0[j].x; s0.y += m * a0[j].y; s0.z += m * a0[j].z; s0.w += m * a0[j].w;
            s1.x += m * a1[j].x; s1.y += m * a1[j].y; s1.z += m * a1[j].z; s1.w += m * a1[j].w;
        }
        ((float4*)red[wv])[lane]      = s0;
        ((float4*)red[wv])[lane + 64] = s1;
    }
    __syncthreads();

    float g = 0.f;
    #pragma unroll
    for (int w = 0; w < 8; ++w) g += red[w][tid];
    const float gi = g * (1.f / 64.f);      // exact /64, matches reference mean

    // ---- gate scores ----
    {
        float p[E];
        #pragma unroll
        for (int e = 0; e < E; ++e) p[e] = gi * gate_W[e * D + tid];
        #pragma unroll
        for (int e = 0; e < E; ++e) {
            float v = p[e];
            #pragma unroll
            for (int off = 32; off; off >>= 1) v += __shfl_xor(v, off, 64);
            if (lane == 0) gred[wv * E + e] = v;
        }
    }
    __syncthreads();
    if (tid < E) {
        float s = gate_b[tid];
        #pragma unroll
        for (int w = 0; w < 8; ++w) s += gred[w * E + tid];
        gsc[tid] = s;
    }
    __syncthreads();

    // ---- top-2 + softmax over the two (first-index tie-break like lax.top_k) ----
    if (tid == 0) {
        int b0 = 0; float v0 = gsc[0];
        for (int e = 1; e < E; ++e) if (gsc[e] > v0) { v0 = gsc[e]; b0 = e; }
        int b1 = -1; float v1 = -3.4e38f;
        for (int e = 0; e < E; ++e) if (e != b0 && gsc[e] > v1) { v1 = gsc[e]; b1 = e; }
        float ex  = expf(v1 - v0);
        float inv = 1.f / (1.f + ex);
        wsel[0] = inv; wsel[1] = ex * inv;
        esel[0] = b0;  esel[1] = b1;
        float cnt = 0.f;
        for (int l = 0; l < L; ++l) cnt += msk[l];
        allpad = (cnt == 0.f) ? 1 : 0;
    }
    __syncthreads();

    // ---- score dots for the 2 selected experts (proj rows read direct, L2-hot) ----
    {
        const float4* pe0 = (const float4*)(proj + esel[0] * D);
        const float4* pe1 = (const float4*)(proj + esel[1] * D);
        float4 b00 = pe0[lane], b01 = pe0[lane + 64];
        float4 b10 = pe1[lane], b11 = pe1[lane + 64];
        #pragma unroll
        for (int j = 0; j < 8; ++j) {
            float s0 = a0[j].x*b00.x + a0[j].y*b00.y + a0[j].z*b00.z + a0[j].w*b00.w
                     + a1[j].x*b01.x + a1[j].y*b01.y + a1[j].z*b01.z + a1[j].w*b01.w;
            float s1 = a0[j].x*b10.x + a0[j].y*b10.y + a0[j].z*b10.z + a0[j].w*b10.w
                     + a1[j].x*b11.x + a1[j].y*b11.y + a1[j].z*b11.z + a1[j].w*b11.w;
            #pragma unroll
            for (int off = 32; off; off >>= 1) {
                s0 += __shfl_xor(s0, off, 64);
                s1 += __shfl_xor(s1, off, 64);
            }
            if (lane == 0) {
                int l = wv * 8 + j;
                bool real = (msk[l] != 0.f);
                scr[0][l] = real ? s0 : NEG_INF;
                scr[1][l] = real ? s1 : NEG_INF;
            }
        }
    }
    __syncthreads();

    // ---- masked softmax over L for both selected experts ----
    if (tid < 128) {
        int k = wv;                          // 0 or 1
        float s = scr[k][lane];
        float m = s;
        #pragma unroll
        for (int off = 32; off; off >>= 1) m = fmaxf(m, __shfl_xor(m, off, 64));
        float pex = expf(s - m);
        float sum = pex;
        #pragma unroll
        for (int off = 32; off; off >>= 1) sum += __shfl_xor(sum, off, 64);
        att2[k][lane] = pex / sum;
    }
    __syncthreads();
    if (tid < L) cf[tid] = wsel[0] * att2[0][tid] + wsel[1] * att2[1][tid];
    __syncthreads();

    // ---- pooled: in-wave partial over 8 tokens, cross-wave via LDS ----
    {
        float4 s0 = {0.f, 0.f, 0.f, 0.f}, s1 = {0.f, 0.f, 0.f, 0.f};
        #pragma unroll
        for (int j = 0; j < 8; ++j) {
            float c = cf[wv * 8 + j];
            s0.x += c * a0[j].x; s0.y += c * a0[j].y; s0.z += c * a0[j].z; s0.w += c * a0[j].w;
            s1.x += c * a1[j].x; s1.y += c * a1[j].y; s1.z += c * a1[j].z; s1.w += c * a1[j].w;
        }
        ((float4*)red[wv])[lane]      = s0;
        ((float4*)red[wv])[lane + 64] = s1;
    }
    __syncthreads();

    float acc = 0.f;
    #pragma unroll
    for (int w = 0; w < 8; ++w) acc += red[w][tid];
    if (allpad) acc = 0.f;
    pooled[(size_t)n * D + tid] = acc;
}

// ---------- Kernel C: out = gelu(pooled @ wT + b); wave handles 2 rows ----------
__launch_bounds__(256, 4)
__global__ void out_kernel(const float* __restrict__ pooled,
                           const float* __restrict__ wT,     // [D][F]
                           const float* __restrict__ trans_b,
                           float* __restrict__ out) {
    __shared__ float pl[8 * D];             // 16 KiB
    const int tid  = threadIdx.x;
    const int lane = tid & 63;
    const int w    = tid >> 6;              // wave -> rows 2w, 2w+1
    const int n0   = blockIdx.x * 8;

    {
        const float4* src = (const float4*)(pooled + (size_t)n0 * D);
        float4* dst = (float4*)pl;
        #pragma unroll
        for (int i = 0; i < 4; ++i) dst[tid + 256 * i] = src[tid + 256 * i];
    }
    __syncthreads();

    const float* pl0 = pl + (2 * w) * D;
    const float* pl1 = pl0 + D;
    const float4* wT4 = (const float4*)wT;  // [D][F/4]
    float4 acc0 = {0.f,0.f,0.f,0.f}, acc1 = {0.f,0.f,0.f,0.f};
    #pragma unroll 4
    for (int d = 0; d < D; ++d) {
        float4 wt = wT4[d * 64 + lane];     // coalesced 16B/lane
        float p0 = pl0[d], p1 = pl1[d];     // LDS broadcast
        acc0.x += p0*wt.x; acc0.y += p0*wt.y; acc0.z += p0*wt.z; acc0.w += p0*wt.w;
        acc1.x += p1*wt.x; acc1.y += p1*wt.y; acc1.z += p1*wt.z; acc1.w += p1*wt.w;
    }

    float4 b4 = ((const float4*)trans_b)[lane];
    float4 o0, o1;
    #define GELU(v) (0.5f * (v) * (1.f + erff((v) * 0.70710678118654752f)))
    o0.x = GELU(acc0.x + b4.x); o0.y = GELU(acc0.y + b4.y);
    o0.z = GELU(acc0.z + b4.z); o0.w = GELU(acc0.w + b4.w);
    o1.x = GELU(acc1.x + b4.x); o1.y = GELU(acc1.y + b4.y);
    o1.z = GELU(acc1.z + b4.z); o1.w = GELU(acc1.w + b4.w);
    #undef GELU
    ((float4*)(out + (size_t)(n0 + 2 * w) * F))[lane]     = o0;
    ((float4*)(out + (size_t)(n0 + 2 * w + 1) * F))[lane] = o1;
}

extern "C" void kernel_launch(void* const* d_in, const int* in_sizes, int n_in,
                              void* d_out, int out_size, void* d_ws, size_t ws_size,
                              hipStream_t stream) {
    const int*   sample    = (const int*)d_in[0];
    const float* emb_table = (const float*)d_in[1];
    const float* expert_q  = (const float*)d_in[2];
    const float* expert_Wk = (const float*)d_in[3];
    const float* gate_W    = (const float*)d_in[4];
    const float* gate_b    = (const float*)d_in[5];
    const float* trans_W   = (const float*)d_in[6];
    const float* trans_b   = (const float*)d_in[7];
    float* out = (float*)d_out;

    const int N = in_sizes[0] / L;                 // B*T = 2048

    float* proj   = (float*)d_ws;                  // E*D
    float* pooled = proj + E * D;                  // N*D
    float* part   = pooled + (size_t)N * D;        // E*8*D
    float* wT     = part + E * 8 * D;              // D*F
    (void)ws_size; (void)n_in; (void)out_size;

    projA_kernel<<<E * 8, D, 0, stream>>>(expert_Wk, expert_q, part);
    projB_kernel<<<(E * D) / 256, 256, 0, stream>>>(part, proj);
    transp_kernel<<<D, F, 0, stream>>>(trans_W, wT);
    row_kernel<<<N, 512, 0, stream>>>(sample, emb_table, proj, gate_W, gate_b, pooled);
    out_kernel<<<N / 8, 256, 0, stream>>>(pooled, wT, trans_b, out);
}